// Round 8
// baseline (454.410 us; speedup 1.0000x reference)
//
#include <hip/hip_runtime.h>
#include <hip/hip_bf16.h>
#include <stdint.h>
#include <stddef.h>

// Problem constants
#define BATCH   4096
#define INDIM   512
#define OUTDIM  512
#define NH      32
#define KKDIM   64                 // 2*NH k-values per input dim
#define INV2PI  0.15915494309189535f

// BARRIER-FREE design. Rounds 0-7: every schedule with a block-wide barrier
// per dim lands at 190-230us, all pipes <=50% (m233's 2-phase overhead).
// Root cause: barriers exist only to protect the SHARED B tile. Fix: wave
// grid 1x4 -- each wave owns a 32-col B slice and DMAs its own private 4KB
// per dim into its own LDS dbuf. No shared LDS state -> ZERO barriers; the
// only hazard is the wave's own stage vs its own reads, closed by per-wave
// counted vmcnt (4 ops/stage, exact). Waves drift freely (m114 overlap).
// BM=64 keeps per-lane trig 4 rows (per-CU demand = R4) and L2 B-traffic at
// ~1.8 TB/s/XCD (BM=32 would hit 3.7, near the 4.3 ceiling).
#define BM       64
#define BN       128
#define THREADS  256
#define KSPLIT   8
#define DIMS_PER_WG (INDIM / KSPLIT)     // 64 input dims per workgroup
#define CHUNK_COLS  256
#define CHUNK_ELEMS (CHUNK_COLS * KKDIM) // 16384 bf16 = 32 KB per (cb2, dim) chunk

#define SLICE_BYTES   4096                     // [32 col][64 kk] bf16 per wave per dim
#define BUF_BYTES     (4 * SLICE_BYTES)        // 4 waves
#define SMEM_BYTES    (2 * BUF_BYTES)          // 32768 -> 4 blocks/CU

typedef short  bhalf8  __attribute__((ext_vector_type(8)));  // 8 bf16 (4 VGPRs)
typedef float  vfloat4 __attribute__((ext_vector_type(4)));

union AFrag { uint4 u; bhalf8 h; };

__device__ __forceinline__ unsigned pack_bf16(float a, float b) {
    union { __hip_bfloat162 h2; unsigned u; } cv;
    cv.h2 = __float22bfloat162_rn(float2{a, b});   // cos in low half (kk even), sin in high
    return cv.u;
}

__device__ __forceinline__ void async_copy16(const void* gsrc, void* ldst) {
    __builtin_amdgcn_global_load_lds(
        (const __attribute__((address_space(1))) void*)(uintptr_t)gsrc,
        (__attribute__((address_space(3))) void*)(uint32_t)(uintptr_t)ldst,
        16, 0, 0);
}

// ---------------------------------------------------------------------------
// Prepass (proven since round 1): fourier_coeffs fp32 [512,32,2,512] -> bf16
// chunks [256 col][64 kk] with 16B-unit swizzle pc = (kk>>3) ^ (col&7) baked
// in. Main kernel DMAs 4KB 32-col sub-slices. Both global sides coalesced.
// ---------------------------------------------------------------------------
__global__ __launch_bounds__(256) void fkan_prepass(const float* __restrict__ coeffs,
                                                    unsigned short* __restrict__ Bt) {
    __shared__ float lds[64][260];   // pad 260: conflict-free f32x4 writes + scalar reads
    const int t  = threadIdx.x;
    const int cb = blockIdx.x & 1;
    const int i  = blockIdx.x >> 1;
    const float* __restrict__ src = coeffs + (size_t)i * (KKDIM * OUTDIM) + cb * CHUNK_COLS;
    unsigned short* __restrict__ chunk = Bt + (size_t)(cb * INDIM + i) * CHUNK_ELEMS;
#pragma unroll
    for (int rd = 0; rd < 16; ++rd) {
        const int r  = rd * 4 + (t >> 6);       // each wave loads one kk-row, coalesced
        const int c4 = (t & 63) * 4;
        const float4 v = *(const float4*)(src + (size_t)r * OUTDIM + c4);
        *(float4*)&lds[r][c4] = v;
    }
    __syncthreads();
#pragma unroll
    for (int s = 0; s < 8; ++s) {
        const int unit = t + s * 256;          // 2048 16B-units per chunk
        const int col  = unit >> 3;
        const int pc   = unit & 7;             // physical 16B slot in this col's row
        const int kb   = (pc ^ (col & 7)) * 8; // logical kk base held in this slot
        uint4 o;
        o.x = pack_bf16(lds[kb + 0][col], lds[kb + 1][col]);
        o.y = pack_bf16(lds[kb + 2][col], lds[kb + 3][col]);
        o.z = pack_bf16(lds[kb + 4][col], lds[kb + 5][col]);
        o.w = pack_bf16(lds[kb + 6][col], lds[kb + 7][col]);
        ((uint4*)chunk)[unit] = o;             // lane-contiguous coalesced store
    }
}

// out[b,o] = bias[o]
__global__ __launch_bounds__(256) void fkan_bias_init(const float* __restrict__ bias,
                                                      float* __restrict__ out) {
    const int idx = blockIdx.x * 256 + threadIdx.x;       // 524288 float4s
    ((float4*)out)[idx] = ((const float4*)bias)[idx & 127];
}

// ---------------------------------------------------------------------------
// Main fused kernel helpers
// ---------------------------------------------------------------------------
// cos/sin((k0f+j)*rv) j=0..3 -> *a0, and ((k1f+j)*rv) -> *a1, packed bf16
// pairs. Slot-identical to the proven layout of rounds 0-7.
__device__ __forceinline__ void make_av(float rv, float k0f, float k1f,
                                        bhalf8* a0, bhalf8* a1) {
    const float cd = __builtin_amdgcn_cosf(rv);   // step e^{ix} (revolution domain)
    const float sd = __builtin_amdgcn_sinf(rv);
    AFrag A;
    float c = __builtin_amdgcn_cosf(k0f * rv);
    float s = __builtin_amdgcn_sinf(k0f * rv);
    A.u.x = pack_bf16(c, s);
    { const float nc = c*cd - s*sd, ns = s*cd + c*sd; c = nc; s = ns; }
    A.u.y = pack_bf16(c, s);
    { const float nc = c*cd - s*sd, ns = s*cd + c*sd; c = nc; s = ns; }
    A.u.z = pack_bf16(c, s);
    { const float nc = c*cd - s*sd, ns = s*cd + c*sd; c = nc; s = ns; }
    A.u.w = pack_bf16(c, s);
    *a0 = A.h;
    c = __builtin_amdgcn_cosf(k1f * rv);
    s = __builtin_amdgcn_sinf(k1f * rv);
    A.u.x = pack_bf16(c, s);
    { const float nc = c*cd - s*sd, ns = s*cd + c*sd; c = nc; s = ns; }
    A.u.y = pack_bf16(c, s);
    { const float nc = c*cd - s*sd, ns = s*cd + c*sd; c = nc; s = ns; }
    A.u.z = pack_bf16(c, s);
    { const float nc = c*cd - s*sd, ns = s*cd + c*sd; c = nc; s = ns; }
    A.u.w = pack_bf16(c, s);
    *a1 = A.h;
}

// Per-wave counted wait: the wave's own stage(it) 4 ops are the oldest
// outstanding; N newest ops (next stage / x prefetch) stay in flight.
#define WAITV(N) asm volatile("s_waitcnt vmcnt(" #N ")" ::: "memory")

// One dim body (per wave, barrier-free). Order: [x prefetch at group head]
// -> stage(it+1) into 1-p -> counted wait (stage(it) landed; stage(it+1)
// flying) -> 4 ds_read_b128 B frags -> 4-row register trig (hides lgkm)
// -> 16 MFMA. C: float2 component (x/y) of the current x pair.
#define FKAN_BODY(IT, C, XSTMT, DO_STAGE, N)                                    \
    {                                                                           \
        XSTMT;                                                                  \
        if (DO_STAGE) {                                                         \
            const char* gsrc = slicebase + (size_t)((IT) + 1) * 32768;          \
            char* ldst = smem + (((IT) + 1) & 1) * BUF_BYTES + w * SLICE_BYTES; \
            async_copy16(gsrc + lane * 16,        ldst + lane * 16);            \
            async_copy16(gsrc + lane * 16 + 1024, ldst + lane * 16 + 1024);     \
            async_copy16(gsrc + lane * 16 + 2048, ldst + lane * 16 + 2048);     \
            async_copy16(gsrc + lane * 16 + 3072, ldst + lane * 16 + 3072);     \
        }                                                                       \
        WAITV(N);                                                               \
        const char* Bb = smem + ((IT) & 1) * BUF_BYTES + w * SLICE_BYTES;       \
        const bhalf8 b00 = *(const bhalf8*)(Bb + (0 * 16 + fr) * 128 + off0);   \
        const bhalf8 b01 = *(const bhalf8*)(Bb + (1 * 16 + fr) * 128 + off0);   \
        const bhalf8 b10 = *(const bhalf8*)(Bb + (0 * 16 + fr) * 128 + off1);   \
        const bhalf8 b11 = *(const bhalf8*)(Bb + (1 * 16 + fr) * 128 + off1);   \
        bhalf8 a0[4], a1[4];                                                    \
        make_av(cq0.C * INV2PI, k0f, k1f, &a0[0], &a1[0]);                      \
        make_av(cq1.C * INV2PI, k0f, k1f, &a0[1], &a1[1]);                      \
        make_av(cq2.C * INV2PI, k0f, k1f, &a0[2], &a1[2]);                      \
        make_av(cq3.C * INV2PI, k0f, k1f, &a0[3], &a1[3]);                      \
        __builtin_amdgcn_s_setprio(1);                                          \
        _Pragma("unroll")                                                       \
        for (int rt = 0; rt < 4; ++rt) {                                        \
            acc[rt][0] = __builtin_amdgcn_mfma_f32_16x16x32_bf16(               \
                a0[rt], b00, acc[rt][0], 0, 0, 0);                              \
            acc[rt][1] = __builtin_amdgcn_mfma_f32_16x16x32_bf16(               \
                a0[rt], b01, acc[rt][1], 0, 0, 0);                              \
            acc[rt][0] = __builtin_amdgcn_mfma_f32_16x16x32_bf16(               \
                a1[rt], b10, acc[rt][0], 0, 0, 0);                              \
            acc[rt][1] = __builtin_amdgcn_mfma_f32_16x16x32_bf16(               \
                a1[rt], b11, acc[rt][1], 0, 0, 0);                              \
        }                                                                       \
        __builtin_amdgcn_s_setprio(0);                                          \
    }

#define XLOAD(G1) { nq0 = xr0[G1]; nq1 = xr1[G1]; nq2 = xr2[G1]; nq3 = xr3[G1]; }
#define XNOP      {}

// ---------------------------------------------------------------------------
// Main kernel: grid 2048 (= 64 rowblocks x 4 colblocks x 8 ksplits), 256 thr.
// grp = blockIdx&31 = cb4*8 + kq -> XCD (= blockIdx%8) is kq: per-XCD L2
// working set = 64 dims x 32KB B + 1MB x ~ 3MB <= 4MB (proven rounds 4-6).
// Wave grid 1x4: wave w owns cols colbase + w*32.., rows rowbase..+63.
// Per wave-dim: 4 private async DMAs, 4 ds_read_b128, 4-row register trig,
// 16 MFMA. NO __syncthreads / s_barrier anywhere in the loop.
// ---------------------------------------------------------------------------
__global__ __launch_bounds__(THREADS, 4) void fkan_main(const float* __restrict__ x,
                                                        const unsigned short* __restrict__ Bt,
                                                        float* __restrict__ out) {
    __shared__ char smem[SMEM_BYTES];
    const int t      = threadIdx.x;
    const int grp    = blockIdx.x & 31;
    const int member = blockIdx.x >> 5;
    const int kq      = grp & 7;          // ksplit -> XCD
    const int cb4     = grp >> 3;         // col block (128 cols)
    const int cb2     = cb4 >> 1;         // prepass chunk (256-col) index
    const int rowbase = member * BM;
    const int colbase = cb4 * BN;
    const int dimbase = kq * DIMS_PER_WG;

    const int lane = t & 63;
    const int w    = t >> 6;       // wave grid 1x4; wave tile 64 rows x 32 cols
    const int fr   = lane & 15;    // row/col within 16x16 tile
    const int fq   = lane >> 4;    // quad -> k-chunk of 8 kk (4 harmonics)
    const int fx   = lane & 7;     // xor swizzle key (== col&7; col = ct*16+fr)
    const int off0 = (fq ^ fx) * 16;         // ks=0 swizzled slot
    const int off1 = ((4 + fq) ^ fx) * 16;   // ks=1 swizzled slot

    const float k0f = (float)(fq * 4 + 1);    // ks=0 base harmonic
    const float k1f = (float)(fq * 4 + 17);   // ks=1 base harmonic

    // Per-lane x rows rt*16 + fr (rt 0..3), read as float2 pairs of dims.
    const float2* __restrict__ xr0 =
        (const float2*)(x + (size_t)(rowbase +  0 + fr) * INDIM + dimbase);
    const float2* __restrict__ xr1 =
        (const float2*)(x + (size_t)(rowbase + 16 + fr) * INDIM + dimbase);
    const float2* __restrict__ xr2 =
        (const float2*)(x + (size_t)(rowbase + 32 + fr) * INDIM + dimbase);
    const float2* __restrict__ xr3 =
        (const float2*)(x + (size_t)(rowbase + 48 + fr) * INDIM + dimbase);

    // This wave's private 4KB column slice within the (cb2, dim) 32KB chunk.
    const char* __restrict__ slicebase =
        (const char*)(Bt + (size_t)(cb2 * INDIM + dimbase) * CHUNK_ELEMS)
        + (cb4 & 1) * 16384 + w * SLICE_BYTES;

    vfloat4 acc[4][2];
#pragma unroll
    for (int a = 0; a < 4; ++a) { acc[a][0] = (vfloat4)0.0f; acc[a][1] = (vfloat4)0.0f; }

    // Prologue: x pair 0; this wave's B slice for dim 0 into buf0. Body 0's
    // counted wait enforces completion -- no drain, no barrier.
    float2 cq0 = xr0[0], cq1 = xr1[0], cq2 = xr2[0], cq3 = xr3[0];
    float2 nq0, nq1, nq2, nq3;
    {
        char* ldst = smem + w * SLICE_BYTES;
        async_copy16(slicebase + lane * 16,        ldst + lane * 16);
        async_copy16(slicebase + lane * 16 + 1024, ldst + lane * 16 + 1024);
        async_copy16(slicebase + lane * 16 + 2048, ldst + lane * 16 + 2048);
        async_copy16(slicebase + lane * 16 + 3072, ldst + lane * 16 + 3072);
    }

#pragma unroll 1
    for (int g = 0; g < 31; ++g) {          // dims 0..61 in pairs
        const int it0 = g * 2;
        // j=0: x pair g+1 (4 ops) + stage(it0+1) (4 ops) newer than stage(it0) -> 8
        FKAN_BODY(it0 + 0, x, XLOAD(g + 1), true, 8);
        // j=1: only stage(it0+2) newer -> 4 (also drains any x leftovers, older)
        FKAN_BODY(it0 + 1, y, XNOP,         true, 4);
        cq0 = nq0; cq1 = nq1; cq2 = nq2; cq3 = nq3;
    }
    // Tail pair (dims 62, 63): no x prefetch; dim 63 has nothing newer.
    FKAN_BODY(62, x, XNOP, true,  4);
    FKAN_BODY(63, y, XNOP, false, 0);

    // Epilogue: C/D layout col=lane&15, row=quad*4+reg (m89). KSPLIT partials via atomics.
#pragma unroll
    for (int rt = 0; rt < 4; ++rt) {
#pragma unroll
        for (int ct = 0; ct < 2; ++ct) {
            const int col  = colbase + w * 32 + ct * 16 + fr;
            const int row0 = rowbase + rt * 16 + fq * 4;
#pragma unroll
            for (int r = 0; r < 4; ++r)
                atomicAdd(out + (size_t)(row0 + r) * OUTDIM + col, acc[rt][ct][r]);
        }
    }
}

// ---------------------------------------------------------------------------
// Fallback (only if ws too small for the 32MB bf16 B): slow but correct fp32.
// ---------------------------------------------------------------------------
__global__ __launch_bounds__(256) void fkan_naive(const float* __restrict__ x,
                                                  const float* __restrict__ coeffs,
                                                  const float* __restrict__ bias,
                                                  float* __restrict__ out) {
    const int b = blockIdx.x >> 1;
    const int o = ((blockIdx.x & 1) << 8) + threadIdx.x;
    float acc = bias[o];
    const float* xrow = x + (size_t)b * INDIM;
    for (int i = 0; i < INDIM; ++i) {
        const float rv = xrow[i] * INV2PI;
        const float cd = __builtin_amdgcn_cosf(rv);
        const float sd = __builtin_amdgcn_sinf(rv);
        float c = cd, s = sd;
        const float* cp = coeffs + (size_t)i * (KKDIM * OUTDIM) + o;
#pragma unroll 4
        for (int g = 0; g < NH; ++g) {
            acc += c * cp[g * 2 * OUTDIM] + s * cp[(g * 2 + 1) * OUTDIM];
            const float nc = c * cd - s * sd;
            const float ns = s * cd + c * sd;
            c = nc; s = ns;
        }
    }
    out[(size_t)b * OUTDIM + o] = acc;
}

extern "C" void kernel_launch(void* const* d_in, const int* in_sizes, int n_in,
                              void* d_out, int out_size, void* d_ws, size_t ws_size,
                              hipStream_t stream) {
    (void)in_sizes; (void)n_in; (void)out_size;
    const float* x      = (const float*)d_in[0];
    const float* coeffs = (const float*)d_in[1];
    const float* bias   = (const float*)d_in[2];
    float* out          = (float*)d_out;

    const size_t bt_bytes = (size_t)2 * INDIM * CHUNK_ELEMS * sizeof(unsigned short); // 32 MiB
    if (ws_size >= bt_bytes) {
        unsigned short* Bt = (unsigned short*)d_ws;
        fkan_prepass<<<2 * INDIM, 256, 0, stream>>>(coeffs, Bt);          // 1024 blocks
        fkan_bias_init<<<(BATCH * OUTDIM) / (4 * 256), 256, 0, stream>>>(bias, out);
        fkan_main<<<(BATCH / BM) * (OUTDIM / BN) * KSPLIT, THREADS, 0, stream>>>(x, Bt, out);
    } else {
        fkan_naive<<<BATCH * 2, 256, 0, stream>>>(x, coeffs, bias, out);
    }
}

// Round 9
// 282.655 us; speedup vs baseline: 1.6077x; 1.6077x over previous
//
#include <hip/hip_runtime.h>
#include <hip/hip_bf16.h>
#include <stdint.h>
#include <stddef.h>

// Problem constants
#define BATCH   4096
#define INDIM   512
#define OUTDIM  512
#define NH      32
#define KKDIM   64                 // 2*NH k-values per input dim
#define INV2PI  0.15915494309189535f

// 2-dims-per-barrier pipeline. Cross-round accounting: R1 (LDS-heavy) and R4
// (VALU-heavy) hit the SAME 190us wall; serial work sums to ~1860 cyc/SIMD
// per dim-interval vs 4650 measured -- ~2800 cyc/interval of fixed barrier
// rendezvous + DMA-drain latency is the binder, not any pipe. Counted-vmcnt
// removal attempts (R5-R7) all failed on bookkeeping; instead AMORTIZE: stage
// TWO dims (32KB) per interval, one __syncthreads, two proven R4 bodies.
// 32 intervals instead of 64. Plain barriers -- no vmcnt fragility.
// LDS = 2 x 32KB dbuf = 64KB -> 2 blocks/CU. x direct from global (L2-hot),
// prefetched one interval ahead (placement harmless under full-drain sync).
#define BM       128
#define BN       128
#define THREADS  256
#define KSPLIT   8
#define DIMS_PER_WG (INDIM / KSPLIT)     // 64 input dims per workgroup
#define CHUNK_COLS  256
#define CHUNK_ELEMS (CHUNK_COLS * KKDIM) // 16384 bf16 = 32 KB per (cb2, dim) chunk

#define PAIR_BYTES    32768                    // 2 dims x 16KB col-half
#define SMEM_BYTES    (2 * PAIR_BYTES)         // 65536 -> 2 blocks/CU

typedef short  bhalf8  __attribute__((ext_vector_type(8)));  // 8 bf16 (4 VGPRs)
typedef float  vfloat4 __attribute__((ext_vector_type(4)));

union AFrag { uint4 u; bhalf8 h; };

__device__ __forceinline__ unsigned pack_bf16(float a, float b) {
    union { __hip_bfloat162 h2; unsigned u; } cv;
    cv.h2 = __float22bfloat162_rn(float2{a, b});   // cos in low half (kk even), sin in high
    return cv.u;
}

__device__ __forceinline__ void async_copy16(const void* gsrc, void* ldst) {
    __builtin_amdgcn_global_load_lds(
        (const __attribute__((address_space(1))) void*)(uintptr_t)gsrc,
        (__attribute__((address_space(3))) void*)(uint32_t)(uintptr_t)ldst,
        16, 0, 0);
}

// ---------------------------------------------------------------------------
// Prepass (proven since round 1) + fused bias broadcast (saves a launch).
// fourier_coeffs fp32 [512,32,2,512] -> bf16 chunks [256 col][64 kk] with
// 16B-unit swizzle pc = (kk>>3) ^ (col&7) baked in. Both global sides
// coalesced. Bias writes issued first so they fly under the LDS transpose.
// ---------------------------------------------------------------------------
__global__ __launch_bounds__(256) void fkan_prepass(const float* __restrict__ coeffs,
                                                    unsigned short* __restrict__ Bt,
                                                    const float* __restrict__ bias,
                                                    float* __restrict__ out) {
    __shared__ float lds[64][260];   // pad 260: conflict-free f32x4 writes + scalar reads
    const int t  = threadIdx.x;
    // out[b,o] = bias[o]: 524288 float4s across 262144 threads (2 each).
    {
        const int gidx = blockIdx.x * 256 + t;
        const float4 bv = ((const float4*)bias)[gidx & 127];
        ((float4*)out)[gidx] = bv;
        ((float4*)out)[gidx + 262144] = bv;
    }
    const int cb = blockIdx.x & 1;
    const int i  = blockIdx.x >> 1;
    const float* __restrict__ src = coeffs + (size_t)i * (KKDIM * OUTDIM) + cb * CHUNK_COLS;
    unsigned short* __restrict__ chunk = Bt + (size_t)(cb * INDIM + i) * CHUNK_ELEMS;
#pragma unroll
    for (int rd = 0; rd < 16; ++rd) {
        const int r  = rd * 4 + (t >> 6);       // each wave loads one kk-row, coalesced
        const int c4 = (t & 63) * 4;
        const float4 v = *(const float4*)(src + (size_t)r * OUTDIM + c4);
        *(float4*)&lds[r][c4] = v;
    }
    __syncthreads();
#pragma unroll
    for (int s = 0; s < 8; ++s) {
        const int unit = t + s * 256;          // 2048 16B-units per chunk
        const int col  = unit >> 3;
        const int pc   = unit & 7;             // physical 16B slot in this col's row
        const int kb   = (pc ^ (col & 7)) * 8; // logical kk base held in this slot
        uint4 o;
        o.x = pack_bf16(lds[kb + 0][col], lds[kb + 1][col]);
        o.y = pack_bf16(lds[kb + 2][col], lds[kb + 3][col]);
        o.z = pack_bf16(lds[kb + 4][col], lds[kb + 5][col]);
        o.w = pack_bf16(lds[kb + 6][col], lds[kb + 7][col]);
        ((uint4*)chunk)[unit] = o;             // lane-contiguous coalesced store
    }
}

// ---------------------------------------------------------------------------
// Main fused kernel helpers
// ---------------------------------------------------------------------------
// Stage dims d0, d0+1 (this block's 16KB col-half each) into 32KB buffer buf.
__device__ __forceinline__ void stage_pair(const char* __restrict__ chunkbase, int d0,
                                           char* smem, int buf, int t) {
#pragma unroll
    for (int dd = 0; dd < 2; ++dd) {
        const char* gsrc = chunkbase + (size_t)(d0 + dd) * 32768;
        char* ldst = smem + buf * PAIR_BYTES + dd * 16384;
#pragma unroll
        for (int s = 0; s < 4; ++s) {
            const int unit = t + s * 256;      // 1024 16B-units per 16KB half
            async_copy16(gsrc + unit * 16, ldst + unit * 16);
        }
    }
}

// cos/sin((k0f+j)*rv) j=0..3 -> *a0, and ((k1f+j)*rv) -> *a1, packed bf16
// pairs. Slot-identical to the proven LDS A-tile layout of rounds 0/1.
__device__ __forceinline__ void make_av(float rv, float k0f, float k1f,
                                        bhalf8* a0, bhalf8* a1) {
    const float cd = __builtin_amdgcn_cosf(rv);   // step e^{ix} (revolution domain)
    const float sd = __builtin_amdgcn_sinf(rv);
    AFrag A;
    float c = __builtin_amdgcn_cosf(k0f * rv);
    float s = __builtin_amdgcn_sinf(k0f * rv);
    A.u.x = pack_bf16(c, s);
    { const float nc = c*cd - s*sd, ns = s*cd + c*sd; c = nc; s = ns; }
    A.u.y = pack_bf16(c, s);
    { const float nc = c*cd - s*sd, ns = s*cd + c*sd; c = nc; s = ns; }
    A.u.z = pack_bf16(c, s);
    { const float nc = c*cd - s*sd, ns = s*cd + c*sd; c = nc; s = ns; }
    A.u.w = pack_bf16(c, s);
    *a0 = A.h;
    c = __builtin_amdgcn_cosf(k1f * rv);
    s = __builtin_amdgcn_sinf(k1f * rv);
    A.u.x = pack_bf16(c, s);
    { const float nc = c*cd - s*sd, ns = s*cd + c*sd; c = nc; s = ns; }
    A.u.y = pack_bf16(c, s);
    { const float nc = c*cd - s*sd, ns = s*cd + c*sd; c = nc; s = ns; }
    A.u.z = pack_bf16(c, s);
    { const float nc = c*cd - s*sd, ns = s*cd + c*sd; c = nc; s = ns; }
    A.u.w = pack_bf16(c, s);
    *a1 = A.h;
}

// One dim's MFMA block: 8 col-tiles x 2 k-slots, consuming frag set (A0,A1).
#define MFMA_BLOCK(Bb, A0, A1)                                                  \
    do {                                                                        \
        _Pragma("unroll")                                                       \
        for (int ct = 0; ct < 8; ++ct) {                                        \
            const int cbyte = (ct * 16 + fr) * 128;                             \
            const bhalf8 b0 = *(const bhalf8*)((Bb) + cbyte + off0);            \
            acc[0][ct] = __builtin_amdgcn_mfma_f32_16x16x32_bf16(               \
                (A0)[0], b0, acc[0][ct], 0, 0, 0);                              \
            acc[1][ct] = __builtin_amdgcn_mfma_f32_16x16x32_bf16(               \
                (A0)[1], b0, acc[1][ct], 0, 0, 0);                              \
            const bhalf8 b1 = *(const bhalf8*)((Bb) + cbyte + off1);            \
            acc[0][ct] = __builtin_amdgcn_mfma_f32_16x16x32_bf16(               \
                (A1)[0], b1, acc[0][ct], 0, 0, 0);                              \
            acc[1][ct] = __builtin_amdgcn_mfma_f32_16x16x32_bf16(               \
                (A1)[1], b1, acc[1][ct], 0, 0, 0);                              \
        }                                                                       \
    } while (0)

// ---------------------------------------------------------------------------
// Main kernel: grid 1024 (= 32 rowblocks x 4 colblocks x 8 ksplits), 256 thr.
// grp = blockIdx&31 = cb4*8 + kq -> XCD (= blockIdx%8) is kq: per-XCD L2
// working set = 64 dims x 32KB B + 1MB x ~ 3MB <= 4MB (proven rounds 4-6).
// Wave grid 4x1 (32x128 tiles, zero trig redundancy, proven R4). Per
// interval: stage next 2 dims, [trig(d) -> 16 ds_read_b128 -> 32 MFMA] x 2,
// ONE __syncthreads -- 32 barrier intervals instead of R4's 64.
// ---------------------------------------------------------------------------
__global__ __launch_bounds__(THREADS, 2) void fkan_main(const float* __restrict__ x,
                                                        const unsigned short* __restrict__ Bt,
                                                        float* __restrict__ out) {
    __shared__ char smem[SMEM_BYTES];
    const int t      = threadIdx.x;
    const int grp    = blockIdx.x & 31;
    const int member = blockIdx.x >> 5;
    const int kq      = grp & 7;          // ksplit -> XCD
    const int cb4     = grp >> 3;         // col block (128 cols)
    const int cb2     = cb4 >> 1;         // prepass chunk (256-col) index
    const int rowbase = member * BM;
    const int colbase = cb4 * BN;
    const int dimbase = kq * DIMS_PER_WG;

    const int lane = t & 63;
    const int w    = t >> 6;       // wave grid 4x1; wave tile 32x128 (rows w*32..)
    const int fr   = lane & 15;    // row/col within 16x16 tile
    const int fq   = lane >> 4;    // quad -> k-chunk of 8 kk (4 harmonics)
    const int fx   = lane & 7;     // xor swizzle key for B (== col&7, tiles 16-aligned)
    const int off0 = (fq ^ fx) * 16;         // ks=0 swizzled slot
    const int off1 = ((4 + fq) ^ fx) * 16;   // ks=1 swizzled slot

    const float k0f = (float)(fq * 4 + 1);    // ks=0 base harmonic
    const float k1f = (float)(fq * 4 + 17);   // ks=1 base harmonic

    // Per-lane x rows (w*32 + {fr, 16+fr}), read as float2 pairs of dims,
    // prefetched one interval ahead. L2-hot (1MB x slice per XCD).
    const float2* __restrict__ xr0 =
        (const float2*)(x + (size_t)(rowbase + w * 32 + fr) * INDIM + dimbase);
    const float2* __restrict__ xr1 =
        (const float2*)(x + (size_t)(rowbase + w * 32 + 16 + fr) * INDIM + dimbase);

    // 16KB col-half of the (cb2, dim) 32KB chunk; dims stride 32KB.
    const char* __restrict__ chunkbase =
        (const char*)(Bt + (size_t)(cb2 * INDIM + dimbase) * CHUNK_ELEMS) + (cb4 & 1) * 16384;

    vfloat4 acc[2][8];
#pragma unroll
    for (int a = 0; a < 2; ++a)
#pragma unroll
        for (int b = 0; b < 8; ++b) acc[a][b] = (vfloat4)0.0f;

    // Prologue: x pair 0; B for dims 0,1 into buf0; one full drain.
    float2 cq0 = xr0[0], cq1 = xr1[0];
    float2 nq0, nq1;
    stage_pair(chunkbase, 0, smem, 0, t);
    __syncthreads();

#pragma unroll 1
    for (int g = 0; g < 32; ++g) {
        const int p = g & 1;
        if (g < 31) {
            stage_pair(chunkbase, 2 * g + 2, smem, p ^ 1, t);   // DMA flies over the body
            nq0 = xr0[g + 1];
            nq1 = xr1[g + 1];
        }
        {   // dim 2g
            bhalf8 a0[2], a1[2];
            make_av(cq0.x * INV2PI, k0f, k1f, &a0[0], &a1[0]);
            make_av(cq1.x * INV2PI, k0f, k1f, &a0[1], &a1[1]);
            const char* Bb = smem + p * PAIR_BYTES;
            __builtin_amdgcn_s_setprio(1);
            MFMA_BLOCK(Bb, a0, a1);
            __builtin_amdgcn_s_setprio(0);
        }
        {   // dim 2g+1
            bhalf8 a0[2], a1[2];
            make_av(cq0.y * INV2PI, k0f, k1f, &a0[0], &a1[0]);
            make_av(cq1.y * INV2PI, k0f, k1f, &a0[1], &a1[1]);
            const char* Bb = smem + p * PAIR_BYTES + 16384;
            __builtin_amdgcn_s_setprio(1);
            MFMA_BLOCK(Bb, a0, a1);
            __builtin_amdgcn_s_setprio(0);
        }
        cq0 = nq0; cq1 = nq1;
        __syncthreads();    // ONE barrier per 2 dims: stage drained, buffers safe
    }

    // Epilogue: C/D layout col=lane&15, row=quad*4+reg (m89). KSPLIT partials via atomics.
#pragma unroll
    for (int rt = 0; rt < 2; ++rt) {
#pragma unroll
        for (int ct = 0; ct < 8; ++ct) {
            const int col  = colbase + ct * 16 + fr;
            const int row0 = rowbase + w * 32 + rt * 16 + fq * 4;
#pragma unroll
            for (int r = 0; r < 4; ++r)
                atomicAdd(out + (size_t)(row0 + r) * OUTDIM + col, acc[rt][ct][r]);
        }
    }
}

// ---------------------------------------------------------------------------
// Fallback (only if ws too small for the 32MB bf16 B): slow but correct fp32.
// ---------------------------------------------------------------------------
__global__ __launch_bounds__(256) void fkan_naive(const float* __restrict__ x,
                                                  const float* __restrict__ coeffs,
                                                  const float* __restrict__ bias,
                                                  float* __restrict__ out) {
    const int b = blockIdx.x >> 1;
    const int o = ((blockIdx.x & 1) << 8) + threadIdx.x;
    float acc = bias[o];
    const float* xrow = x + (size_t)b * INDIM;
    for (int i = 0; i < INDIM; ++i) {
        const float rv = xrow[i] * INV2PI;
        const float cd = __builtin_amdgcn_cosf(rv);
        const float sd = __builtin_amdgcn_sinf(rv);
        float c = cd, s = sd;
        const float* cp = coeffs + (size_t)i * (KKDIM * OUTDIM) + o;
#pragma unroll 4
        for (int g = 0; g < NH; ++g) {
            acc += c * cp[g * 2 * OUTDIM] + s * cp[(g * 2 + 1) * OUTDIM];
            const float nc = c * cd - s * sd;
            const float ns = s * cd + c * sd;
            c = nc; s = ns;
        }
    }
    out[(size_t)b * OUTDIM + o] = acc;
}

extern "C" void kernel_launch(void* const* d_in, const int* in_sizes, int n_in,
                              void* d_out, int out_size, void* d_ws, size_t ws_size,
                              hipStream_t stream) {
    (void)in_sizes; (void)n_in; (void)out_size;
    const float* x      = (const float*)d_in[0];
    const float* coeffs = (const float*)d_in[1];
    const float* bias   = (const float*)d_in[2];
    float* out          = (float*)d_out;

    const size_t bt_bytes = (size_t)2 * INDIM * CHUNK_ELEMS * sizeof(unsigned short); // 32 MiB
    if (ws_size >= bt_bytes) {
        unsigned short* Bt = (unsigned short*)d_ws;
        fkan_prepass<<<2 * INDIM, 256, 0, stream>>>(coeffs, Bt, bias, out);  // + fused bias
        fkan_main<<<(BATCH / BM) * (OUTDIM / BN) * KSPLIT, THREADS, 0, stream>>>(x, Bt, out);
    } else {
        fkan_naive<<<BATCH * 2, 256, 0, stream>>>(x, coeffs, bias, out);
    }
}